// Round 1
// baseline (8023.588 us; speedup 1.0000x reference)
//
#include <hip/hip_runtime.h>

// ---------------------------------------------------------------------------
// MutualRec forward: 5x GATv2 + ChebConv(k=3) + mutualistic MLP + edge dots
// All f32. D = 64 (one wave = one row / one edge).
// ---------------------------------------------------------------------------

#define LRELU_SLOPE 0.2f

// ---- float atomic-max via monotonic unsigned encoding ----
__device__ __forceinline__ unsigned fenc(float f) {
  unsigned u = __float_as_uint(f);
  return (u & 0x80000000u) ? ~u : (u | 0x80000000u);
}
__device__ __forceinline__ float fdec(unsigned u) {
  return (u & 0x80000000u) ? __uint_as_float(u & 0x7fffffffu)
                           : __uint_as_float(~u);
}

// ---- Y[N,64] = X[N,64] @ W[64,64] (+ b) (+= if ACC) ----
template <bool ACC>
__global__ void gemm64_k(const float* __restrict__ X, const float* __restrict__ W,
                         const float* __restrict__ b, float* __restrict__ Y, int N) {
  __shared__ float Ws[64 * 64];
  for (int i = threadIdx.x; i < 64 * 64; i += blockDim.x) Ws[i] = W[i];
  __syncthreads();
  const int lane = threadIdx.x & 63;
  const int wid = (blockIdx.x * blockDim.x + threadIdx.x) >> 6;
  const int nw = (gridDim.x * blockDim.x) >> 6;
  const float bj = b ? b[lane] : 0.0f;
  for (int row = wid; row < N; row += nw) {
    float x = X[row * 64 + lane];
    float acc = bj;
#pragma unroll
    for (int k = 0; k < 64; ++k)
      acc = fmaf(__shfl(x, k, 64), Ws[k * 64 + lane], acc);
    if (ACC) Y[row * 64 + lane] += acc;
    else     Y[row * 64 + lane] = acc;
  }
}

// ---- Y[N,64] = concat(A[N,64], B[N,64]) @ W[128,64] + b ----
__global__ void gemm128_k(const float* __restrict__ A, const float* __restrict__ Bm,
                          const float* __restrict__ W, const float* __restrict__ b,
                          float* __restrict__ Y, int N) {
  __shared__ float Ws[128 * 64];
  for (int i = threadIdx.x; i < 128 * 64; i += blockDim.x) Ws[i] = W[i];
  __syncthreads();
  const int lane = threadIdx.x & 63;
  const int wid = (blockIdx.x * blockDim.x + threadIdx.x) >> 6;
  const int nw = (gridDim.x * blockDim.x) >> 6;
  const float bj = b ? b[lane] : 0.0f;
  for (int row = wid; row < N; row += nw) {
    float a = A[row * 64 + lane];
    float c = Bm[row * 64 + lane];
    float acc = bj;
#pragma unroll
    for (int k = 0; k < 64; ++k)
      acc = fmaf(__shfl(a, k, 64), Ws[k * 64 + lane], acc);
#pragma unroll
    for (int k = 0; k < 64; ++k)
      acc = fmaf(__shfl(c, k, 64), Ws[(64 + k) * 64 + lane], acc);
    Y[row * 64 + lane] = acc;
  }
}

// ---- GAT pass 1: per-edge score + segment max (wave per edge) ----
__global__ void score_k(const float* __restrict__ fs, const float* __restrict__ fd,
                        const float* __restrict__ attn, const int* __restrict__ src,
                        const int* __restrict__ dst, float* __restrict__ sbuf,
                        unsigned* __restrict__ menc, int E) {
  const int lane = threadIdx.x & 63;
  const int e = (blockIdx.x * blockDim.x + threadIdx.x) >> 6;
  if (e >= E) return;
  const int s = src[e], d = dst[e];
  float v = fs[s * 64 + lane] + fd[d * 64 + lane];
  v = v > 0.0f ? v : LRELU_SLOPE * v;
  float p = v * attn[lane];
#pragma unroll
  for (int o = 32; o; o >>= 1) p += __shfl_xor(p, o, 64);
  if (lane == 0) {
    sbuf[e] = p;
    atomicMax(menc + d, fenc(p));
  }
}

// ---- GAT pass 2: exp + segment sum (thread per edge) ----
__global__ void expden_k(const int* __restrict__ dst, const unsigned* __restrict__ menc,
                         float* __restrict__ sbuf, float* __restrict__ den, int E) {
  const int e = blockIdx.x * blockDim.x + threadIdx.x;
  if (e >= E) return;
  const int d = dst[e];
  float ex = __expf(sbuf[e] - fdec(menc[d]));
  sbuf[e] = ex;
  atomicAdd(den + d, ex);
}

// ---- GAT pass 3: weighted aggregate (wave per edge) ----
__global__ void aggr_k(const float* __restrict__ fs, const int* __restrict__ src,
                       const int* __restrict__ dst, const float* __restrict__ sbuf,
                       const float* __restrict__ den, float* __restrict__ out, int E) {
  const int lane = threadIdx.x & 63;
  const int e = (blockIdx.x * blockDim.x + threadIdx.x) >> 6;
  if (e >= E) return;
  const int s = src[e], d = dst[e];
  const float alpha = sbuf[e] / den[d];
  atomicAdd(out + d * 64 + lane, alpha * fs[s * 64 + lane]);
}

// ---- Cheb: in-degree count ----
__global__ void indeg_k(const int* __restrict__ dst, float* __restrict__ deg, int E) {
  const int e = blockIdx.x * blockDim.x + threadIdx.x;
  if (e < E) atomicAdd(deg + dst[e], 1.0f);
}
__global__ void dinv_k(float* __restrict__ deg, int N) {
  const int i = blockIdx.x * blockDim.x + threadIdx.x;
  if (i < N) deg[i] = rsqrtf(fmaxf(deg[i], 1.0f));
}

// ---- Cheb: h[dst] += x[src]*dinv[src]  (wave per edge; dst scaling later) ----
__global__ void ahat_k(const float* __restrict__ x, const float* __restrict__ dinv,
                       const int* __restrict__ src, const int* __restrict__ dst,
                       float* __restrict__ h, int E) {
  const int lane = threadIdx.x & 63;
  const int e = (blockIdx.x * blockDim.x + threadIdx.x) >> 6;
  if (e >= E) return;
  const int s = src[e], d = dst[e];
  atomicAdd(h + d * 64 + lane, x[s * 64 + lane] * dinv[s]);
}

// ---- T1 = -re*(dinv*h) + (re-1)*T0 ----
__global__ void t1_k(const float* __restrict__ h, const float* __restrict__ T0,
                     const float* __restrict__ dinv, const float* __restrict__ lam,
                     float* __restrict__ T1, int total) {
  const int i = blockIdx.x * blockDim.x + threadIdx.x;
  if (i >= total) return;
  const float re = 2.0f / lam[0];
  const int u = i >> 6;
  T1[i] = -re * (dinv[u] * h[i]) + (re - 1.0f) * T0[i];
}

// ---- T2 = -2re*(dinv*h2) + 2(re-1)*T1 - T0 ----
__global__ void t2_k(const float* __restrict__ h2, const float* __restrict__ T1,
                     const float* __restrict__ T0, const float* __restrict__ dinv,
                     const float* __restrict__ lam, float* __restrict__ T2, int total) {
  const int i = blockIdx.x * blockDim.x + threadIdx.x;
  if (i >= total) return;
  const float re = 2.0f / lam[0];
  const int u = i >> 6;
  T2[i] = -2.0f * re * (dinv[u] * h2[i]) + 2.0f * (re - 1.0f) * T1[i] - T0[i];
}

// ---- mutualistic: mP = (p*s)*softmax(p), mS = (p*s)*softmax(s) (wave/row) ----
__global__ void mut_k(const float* __restrict__ hP, const float* __restrict__ hS,
                      float* __restrict__ mP, float* __restrict__ mS, int N) {
  const int lane = threadIdx.x & 63;
  const int u = (blockIdx.x * blockDim.x + threadIdx.x) >> 6;
  if (u >= N) return;
  const float p = hP[u * 64 + lane];
  const float s = hS[u * 64 + lane];
  const float m = p * s;
  float mxp = p, mxs = s;
#pragma unroll
  for (int o = 32; o; o >>= 1) {
    mxp = fmaxf(mxp, __shfl_xor(mxp, o, 64));
    mxs = fmaxf(mxs, __shfl_xor(mxs, o, 64));
  }
  float ep = __expf(p - mxp);
  float es = __expf(s - mxs);
  float sp = ep, ss = es;
#pragma unroll
  for (int o = 32; o; o >>= 1) {
    sp += __shfl_xor(sp, o, 64);
    ss += __shfl_xor(ss, o, 64);
  }
  mP[u * 64 + lane] = m * (ep / sp);
  mS[u * 64 + lane] = m * (es / ss);
}

// ---- edge dot: out[e] = <A[src[e]], B[dst[e]]> (wave per edge) ----
__global__ void dot_k(const float* __restrict__ A, const float* __restrict__ Bm,
                      const int* __restrict__ src, const int* __restrict__ dst,
                      float* __restrict__ out, int E) {
  const int lane = threadIdx.x & 63;
  const int e = (blockIdx.x * blockDim.x + threadIdx.x) >> 6;
  if (e >= E) return;
  float p = A[src[e] * 64 + lane] * Bm[dst[e] * 64 + lane];
#pragma unroll
  for (int o = 32; o; o >>= 1) p += __shfl_xor(p, o, 64);
  if (lane == 0) out[e] = p;
}

// ---------------------------------------------------------------------------

static void run_gat(const float* hsrc, int Ns, const float* hdst, int Nd,
                    const float* Wsrc, const float* bsrc,
                    const float* Wdst, const float* bdst, const float* attn,
                    const int* src, const int* dst, int E,
                    float* fs, float* fd, float* out,
                    float* sbuf, unsigned* menc, float* den, hipStream_t stream) {
  gemm64_k<false><<<(Ns + 3) / 4, 256, 0, stream>>>(hsrc, Wsrc, bsrc, fs, Ns);
  gemm64_k<false><<<(Nd + 3) / 4, 256, 0, stream>>>(hdst, Wdst, bdst, fd, Nd);
  hipMemsetAsync(menc, 0, (size_t)Nd * 4, stream);
  hipMemsetAsync(den, 0, (size_t)Nd * 4, stream);
  hipMemsetAsync(out, 0, (size_t)Nd * 64 * 4, stream);
  score_k<<<(E + 3) / 4, 256, 0, stream>>>(fs, fd, attn, src, dst, sbuf, menc, E);
  expden_k<<<(E + 255) / 256, 256, 0, stream>>>(dst, menc, sbuf, den, E);
  aggr_k<<<(E + 3) / 4, 256, 0, stream>>>(fs, src, dst, sbuf, den, out, E);
}

extern "C" void kernel_launch(void* const* d_in, const int* in_sizes, int n_in,
                              void* d_out, int out_size, void* d_ws, size_t ws_size,
                              hipStream_t stream) {
  const float* user_emb = (const float*)d_in[0];
  const float* item_emb = (const float*)d_in[1];
  const int* rate_src = (const int*)d_in[2];
  const int* rate_dst = (const int*)d_in[3];
  const int* link_src = (const int*)d_in[4];
  const int* link_dst = (const int*)d_in[5];
  const int* neg_rate_src = (const int*)d_in[6];
  const int* neg_rate_dst = (const int*)d_in[7];
  const int* neg_link_src = (const int*)d_in[8];
  const int* neg_link_dst = (const int*)d_in[9];
  const float* lam = (const float*)d_in[10];
  const float* gat_Wsrc = (const float*)d_in[11];
  const float* gat_bsrc = (const float*)d_in[12];
  const float* gat_Wdst = (const float*)d_in[13];
  const float* gat_bdst = (const float*)d_in[14];
  const float* gat_attn = (const float*)d_in[15];
  const float* W_out = (const float*)d_in[16];
  const float* b_out = (const float*)d_in[17];
  const float* cheb_W = (const float*)d_in[18];
  const float* cheb_b = (const float*)d_in[19];
  const float* Wc = (const float*)d_in[20];
  const float* bc = (const float*)d_in[21];
  const float* Wsm = (const float*)d_in[22];
  const float* bs = (const float*)d_in[23];
  const float* WpP = (const float*)d_in[24];
  const float* bpP = (const float*)d_in[25];
  const float* WpS = (const float*)d_in[26];
  const float* bpS = (const float*)d_in[27];

  const int NU = in_sizes[0] / 64;
  const int NI = in_sizes[1] / 64;
  const int NR = in_sizes[2];
  const int NL = in_sizes[4];
  const int NMAX = NU > NI ? NU : NI;
  const size_t MAT = (size_t)NMAX * 64;

  float* ws = (float*)d_ws;
  float* B0 = ws + 0 * MAT;  // fs scratch / cheb h
  float* B1 = ws + 1 * MAT;  // fd scratch
  float* B2 = ws + 2 * MAT;  // h1_item -> T1 -> h_mP
  float* B3 = ws + 3 * MAT;  // h2_user -> T2 -> h_mS
  float* B4 = ws + 4 * MAT;  // item_infl -> h_uP
  float* B5 = ws + 5 * MAT;  // social_item -> h_uS
  float* B6 = ws + 6 * MAT;  // user_pref -> h_new_P
  float* B7 = ws + 7 * MAT;  // rst -> h_new_S
  float* B8 = ws + 8 * MAT;  // user_social
  float* sbuf = ws + 9 * MAT;                     // NR floats
  unsigned* menc = (unsigned*)(sbuf + NR);        // NU
  float* den = (float*)(menc + NU);               // NU
  float* dinv = den + NU;                         // NU (indeg then dinv)

  const int W64 = 64 * 64, B64 = 64;

  // ---- gat0: user -> item over rate edges ----
  run_gat(user_emb, NU, item_emb, NI,
          gat_Wsrc + 0 * W64, gat_bsrc + 0 * B64, gat_Wdst + 0 * W64,
          gat_bdst + 0 * B64, gat_attn + 0 * B64,
          rate_src, rate_dst, NR, B0, B1, B2, sbuf, menc, den, stream);
  // ---- gat1: item -> user (reverse rate) ----
  run_gat(item_emb, NI, user_emb, NU,
          gat_Wsrc + 1 * W64, gat_bsrc + 1 * B64, gat_Wdst + 1 * W64,
          gat_bdst + 1 * B64, gat_attn + 1 * B64,
          rate_dst, rate_src, NR, B0, B1, B3, sbuf, menc, den, stream);
  // ---- gat2: h1_item -> user (reverse rate) ----
  run_gat(B2, NI, user_emb, NU,
          gat_Wsrc + 2 * W64, gat_bsrc + 2 * B64, gat_Wdst + 2 * W64,
          gat_bdst + 2 * B64, gat_attn + 2 * B64,
          rate_dst, rate_src, NR, B0, B1, B4, sbuf, menc, den, stream);
  // ---- gat3: h2_user -> user over link edges ----
  run_gat(B3, NU, user_emb, NU,
          gat_Wsrc + 3 * W64, gat_bsrc + 3 * B64, gat_Wdst + 3 * W64,
          gat_bdst + 3 * B64, gat_attn + 3 * B64,
          link_src, link_dst, NL, B0, B1, B5, sbuf, menc, den, stream);
  // ---- user_pref = [item_infl, social_item] @ W_out + b_out -> B6 ----
  gemm128_k<<<(NU + 3) / 4, 256, 0, stream>>>(B4, B5, W_out, b_out, B6, NU);

  // ---- ChebConv(k=3) on link graph ----
  hipMemsetAsync(dinv, 0, (size_t)NU * 4, stream);
  indeg_k<<<(NL + 255) / 256, 256, 0, stream>>>(link_dst, dinv, NL);
  dinv_k<<<(NU + 255) / 256, 256, 0, stream>>>(dinv, NU);
  const int TOT = NU * 64;
  // h = ahat(T0) -> B0 ; T1 -> B2
  hipMemsetAsync(B0, 0, (size_t)TOT * 4, stream);
  ahat_k<<<(NL + 3) / 4, 256, 0, stream>>>(user_emb, dinv, link_src, link_dst, B0, NL);
  t1_k<<<(TOT + 255) / 256, 256, 0, stream>>>(B0, user_emb, dinv, lam, B2, TOT);
  // h2 = ahat(T1) -> B0 ; T2 -> B3
  hipMemsetAsync(B0, 0, (size_t)TOT * 4, stream);
  ahat_k<<<(NL + 3) / 4, 256, 0, stream>>>(B2, dinv, link_src, link_dst, B0, NL);
  t2_k<<<(TOT + 255) / 256, 256, 0, stream>>>(B0, B2, user_emb, dinv, lam, B3, TOT);
  // rst = T0@W0 + T1@W1 + T2@W2 + b -> B7
  gemm64_k<false><<<(NU + 3) / 4, 256, 0, stream>>>(user_emb, cheb_W + 0 * W64, nullptr, B7, NU);
  gemm64_k<true><<<(NU + 3) / 4, 256, 0, stream>>>(B2, cheb_W + 1 * W64, nullptr, B7, NU);
  gemm64_k<true><<<(NU + 3) / 4, 256, 0, stream>>>(B3, cheb_W + 2 * W64, cheb_b, B7, NU);

  // ---- gat4: rst -> rst over link edges -> user_social (B8) ----
  run_gat(B7, NU, B7, NU,
          gat_Wsrc + 4 * W64, gat_bsrc + 4 * B64, gat_Wdst + 4 * W64,
          gat_bdst + 4 * B64, gat_attn + 4 * B64,
          link_src, link_dst, NL, B0, B1, B8, sbuf, menc, den, stream);

  // ---- mutualistic ----
  gemm128_k<<<(NU + 3) / 4, 256, 0, stream>>>(B6, user_emb, Wc, bc, B4, NU);   // h_uP
  gemm128_k<<<(NU + 3) / 4, 256, 0, stream>>>(B8, user_emb, Wsm, bs, B5, NU);  // h_uS
  mut_k<<<(NU + 3) / 4, 256, 0, stream>>>(B4, B5, B2, B3, NU);                 // h_mP, h_mS
  gemm128_k<<<(NU + 3) / 4, 256, 0, stream>>>(B2, B4, WpP, bpP, B6, NU);       // h_new_P
  gemm128_k<<<(NU + 3) / 4, 256, 0, stream>>>(B3, B5, WpS, bpS, B7, NU);       // h_new_S

  // ---- predictors ----
  float* out = (float*)d_out;
  dot_k<<<(NR + 3) / 4, 256, 0, stream>>>(B6, item_emb, rate_src, rate_dst, out, NR);
  dot_k<<<(NR + 3) / 4, 256, 0, stream>>>(B6, item_emb, neg_rate_src, neg_rate_dst, out + NR, NR);
  dot_k<<<(NL + 3) / 4, 256, 0, stream>>>(B7, user_emb, link_src, link_dst, out + 2 * (size_t)NR, NL);
  dot_k<<<(NL + 3) / 4, 256, 0, stream>>>(B7, user_emb, neg_link_src, neg_link_dst, out + 2 * (size_t)NR + NL, NL);
}

// Round 2
// 5609.352 us; speedup vs baseline: 1.4304x; 1.4304x over previous
//
#include <hip/hip_runtime.h>

// ---------------------------------------------------------------------------
// MutualRec forward: 5x GATv2 + ChebConv(k=3) + mutualistic MLP + edge dots
// All f32. D = 64 (one wave = one row / one edge).
// R1: fixed 1024-block grid-stride for all GEMMs (W staged once per block,
//     not once per 4 rows); fused Cheb 3-matmul kernel.
// ---------------------------------------------------------------------------

#define LRELU_SLOPE 0.2f
#define GEMM_BLOCKS 1024

// ---- float atomic-max via monotonic unsigned encoding ----
__device__ __forceinline__ unsigned fenc(float f) {
  unsigned u = __float_as_uint(f);
  return (u & 0x80000000u) ? ~u : (u | 0x80000000u);
}
__device__ __forceinline__ float fdec(unsigned u) {
  return (u & 0x80000000u) ? __uint_as_float(u & 0x7fffffffu)
                           : __uint_as_float(~u);
}

// ---- Y[N,64] = X[N,64] @ W[64,64] (+ b) ----
__global__ void gemm64_k(const float* __restrict__ X, const float* __restrict__ W,
                         const float* __restrict__ b, float* __restrict__ Y, int N) {
  __shared__ float Ws[64 * 64];
  for (int i = threadIdx.x; i < 64 * 64; i += blockDim.x) Ws[i] = W[i];
  __syncthreads();
  const int lane = threadIdx.x & 63;
  const int wid = (blockIdx.x * blockDim.x + threadIdx.x) >> 6;
  const int nw = (gridDim.x * blockDim.x) >> 6;
  const float bj = b ? b[lane] : 0.0f;
  for (int row = wid; row < N; row += nw) {
    float x = X[row * 64 + lane];
    float acc = bj;
#pragma unroll
    for (int k = 0; k < 64; ++k)
      acc = fmaf(__shfl(x, k, 64), Ws[k * 64 + lane], acc);
    Y[row * 64 + lane] = acc;
  }
}

// ---- Y[N,64] = concat(A[N,64], B[N,64]) @ W[128,64] + b ----
__global__ void gemm128_k(const float* __restrict__ A, const float* __restrict__ Bm,
                          const float* __restrict__ W, const float* __restrict__ b,
                          float* __restrict__ Y, int N) {
  __shared__ float Ws[128 * 64];
  for (int i = threadIdx.x; i < 128 * 64; i += blockDim.x) Ws[i] = W[i];
  __syncthreads();
  const int lane = threadIdx.x & 63;
  const int wid = (blockIdx.x * blockDim.x + threadIdx.x) >> 6;
  const int nw = (gridDim.x * blockDim.x) >> 6;
  const float bj = b ? b[lane] : 0.0f;
  for (int row = wid; row < N; row += nw) {
    float a = A[row * 64 + lane];
    float c = Bm[row * 64 + lane];
    float acc = bj;
#pragma unroll
    for (int k = 0; k < 64; ++k)
      acc = fmaf(__shfl(a, k, 64), Ws[k * 64 + lane], acc);
#pragma unroll
    for (int k = 0; k < 64; ++k)
      acc = fmaf(__shfl(c, k, 64), Ws[(64 + k) * 64 + lane], acc);
    Y[row * 64 + lane] = acc;
  }
}

// ---- rst = T0@W0 + T1@W1 + T2@W2 + b (fused Cheb combine) ----
__global__ void cheb3_k(const float* __restrict__ T0, const float* __restrict__ T1,
                        const float* __restrict__ T2, const float* __restrict__ W3,
                        const float* __restrict__ b, float* __restrict__ Y, int N) {
  __shared__ float Ws[3 * 64 * 64];
  for (int i = threadIdx.x; i < 3 * 64 * 64; i += blockDim.x) Ws[i] = W3[i];
  __syncthreads();
  const int lane = threadIdx.x & 63;
  const int wid = (blockIdx.x * blockDim.x + threadIdx.x) >> 6;
  const int nw = (gridDim.x * blockDim.x) >> 6;
  const float bj = b[lane];
  for (int row = wid; row < N; row += nw) {
    float x0 = T0[row * 64 + lane];
    float x1 = T1[row * 64 + lane];
    float x2 = T2[row * 64 + lane];
    float acc = bj;
#pragma unroll
    for (int k = 0; k < 64; ++k) {
      acc = fmaf(__shfl(x0, k, 64), Ws[k * 64 + lane], acc);
      acc = fmaf(__shfl(x1, k, 64), Ws[4096 + k * 64 + lane], acc);
      acc = fmaf(__shfl(x2, k, 64), Ws[8192 + k * 64 + lane], acc);
    }
    Y[row * 64 + lane] = acc;
  }
}

// ---- GAT pass 1: per-edge score + segment max (wave per edge) ----
__global__ void score_k(const float* __restrict__ fs, const float* __restrict__ fd,
                        const float* __restrict__ attn, const int* __restrict__ src,
                        const int* __restrict__ dst, float* __restrict__ sbuf,
                        unsigned* __restrict__ menc, int E) {
  const int lane = threadIdx.x & 63;
  const int e = (blockIdx.x * blockDim.x + threadIdx.x) >> 6;
  if (e >= E) return;
  const int s = src[e], d = dst[e];
  float v = fs[s * 64 + lane] + fd[d * 64 + lane];
  v = v > 0.0f ? v : LRELU_SLOPE * v;
  float p = v * attn[lane];
#pragma unroll
  for (int o = 32; o; o >>= 1) p += __shfl_xor(p, o, 64);
  if (lane == 0) {
    sbuf[e] = p;
    atomicMax(menc + d, fenc(p));
  }
}

// ---- GAT pass 2: exp + segment sum (thread per edge) ----
__global__ void expden_k(const int* __restrict__ dst, const unsigned* __restrict__ menc,
                         float* __restrict__ sbuf, float* __restrict__ den, int E) {
  const int e = blockIdx.x * blockDim.x + threadIdx.x;
  if (e >= E) return;
  const int d = dst[e];
  float ex = __expf(sbuf[e] - fdec(menc[d]));
  sbuf[e] = ex;
  atomicAdd(den + d, ex);
}

// ---- GAT pass 3: weighted aggregate (wave per edge) ----
__global__ void aggr_k(const float* __restrict__ fs, const int* __restrict__ src,
                       const int* __restrict__ dst, const float* __restrict__ sbuf,
                       const float* __restrict__ den, float* __restrict__ out, int E) {
  const int lane = threadIdx.x & 63;
  const int e = (blockIdx.x * blockDim.x + threadIdx.x) >> 6;
  if (e >= E) return;
  const int s = src[e], d = dst[e];
  const float alpha = sbuf[e] / den[d];
  atomicAdd(out + d * 64 + lane, alpha * fs[s * 64 + lane]);
}

// ---- Cheb: in-degree count ----
__global__ void indeg_k(const int* __restrict__ dst, float* __restrict__ deg, int E) {
  const int e = blockIdx.x * blockDim.x + threadIdx.x;
  if (e < E) atomicAdd(deg + dst[e], 1.0f);
}
__global__ void dinv_k(float* __restrict__ deg, int N) {
  const int i = blockIdx.x * blockDim.x + threadIdx.x;
  if (i < N) deg[i] = rsqrtf(fmaxf(deg[i], 1.0f));
}

// ---- Cheb: h[dst] += x[src]*dinv[src]  (wave per edge; dst scaling later) ----
__global__ void ahat_k(const float* __restrict__ x, const float* __restrict__ dinv,
                       const int* __restrict__ src, const int* __restrict__ dst,
                       float* __restrict__ h, int E) {
  const int lane = threadIdx.x & 63;
  const int e = (blockIdx.x * blockDim.x + threadIdx.x) >> 6;
  if (e >= E) return;
  const int s = src[e], d = dst[e];
  atomicAdd(h + d * 64 + lane, x[s * 64 + lane] * dinv[s]);
}

// ---- T1 = -re*(dinv*h) + (re-1)*T0 ----
__global__ void t1_k(const float* __restrict__ h, const float* __restrict__ T0,
                     const float* __restrict__ dinv, const float* __restrict__ lam,
                     float* __restrict__ T1, int total) {
  const int i = blockIdx.x * blockDim.x + threadIdx.x;
  if (i >= total) return;
  const float re = 2.0f / lam[0];
  const int u = i >> 6;
  T1[i] = -re * (dinv[u] * h[i]) + (re - 1.0f) * T0[i];
}

// ---- T2 = -2re*(dinv*h2) + 2(re-1)*T1 - T0 ----
__global__ void t2_k(const float* __restrict__ h2, const float* __restrict__ T1,
                     const float* __restrict__ T0, const float* __restrict__ dinv,
                     const float* __restrict__ lam, float* __restrict__ T2, int total) {
  const int i = blockIdx.x * blockDim.x + threadIdx.x;
  if (i >= total) return;
  const float re = 2.0f / lam[0];
  const int u = i >> 6;
  T2[i] = -2.0f * re * (dinv[u] * h2[i]) + 2.0f * (re - 1.0f) * T1[i] - T0[i];
}

// ---- mutualistic: mP = (p*s)*softmax(p), mS = (p*s)*softmax(s) (wave/row) ----
__global__ void mut_k(const float* __restrict__ hP, const float* __restrict__ hS,
                      float* __restrict__ mP, float* __restrict__ mS, int N) {
  const int lane = threadIdx.x & 63;
  const int u = (blockIdx.x * blockDim.x + threadIdx.x) >> 6;
  if (u >= N) return;
  const float p = hP[u * 64 + lane];
  const float s = hS[u * 64 + lane];
  const float m = p * s;
  float mxp = p, mxs = s;
#pragma unroll
  for (int o = 32; o; o >>= 1) {
    mxp = fmaxf(mxp, __shfl_xor(mxp, o, 64));
    mxs = fmaxf(mxs, __shfl_xor(mxs, o, 64));
  }
  float ep = __expf(p - mxp);
  float es = __expf(s - mxs);
  float sp = ep, ss = es;
#pragma unroll
  for (int o = 32; o; o >>= 1) {
    sp += __shfl_xor(sp, o, 64);
    ss += __shfl_xor(ss, o, 64);
  }
  mP[u * 64 + lane] = m * (ep / sp);
  mS[u * 64 + lane] = m * (es / ss);
}

// ---- edge dot: out[e] = <A[src[e]], B[dst[e]]> (wave per edge) ----
__global__ void dot_k(const float* __restrict__ A, const float* __restrict__ Bm,
                      const int* __restrict__ src, const int* __restrict__ dst,
                      float* __restrict__ out, int E) {
  const int lane = threadIdx.x & 63;
  const int e = (blockIdx.x * blockDim.x + threadIdx.x) >> 6;
  if (e >= E) return;
  float p = A[src[e] * 64 + lane] * Bm[dst[e] * 64 + lane];
#pragma unroll
  for (int o = 32; o; o >>= 1) p += __shfl_xor(p, o, 64);
  if (lane == 0) out[e] = p;
}

// ---------------------------------------------------------------------------

static void run_gat(const float* hsrc, int Ns, const float* hdst, int Nd,
                    const float* Wsrc, const float* bsrc,
                    const float* Wdst, const float* bdst, const float* attn,
                    const int* src, const int* dst, int E,
                    float* fs, float* fd, float* out,
                    float* sbuf, unsigned* menc, float* den, hipStream_t stream) {
  gemm64_k<<<GEMM_BLOCKS, 256, 0, stream>>>(hsrc, Wsrc, bsrc, fs, Ns);
  gemm64_k<<<GEMM_BLOCKS, 256, 0, stream>>>(hdst, Wdst, bdst, fd, Nd);
  hipMemsetAsync(menc, 0, (size_t)Nd * 4, stream);
  hipMemsetAsync(den, 0, (size_t)Nd * 4, stream);
  hipMemsetAsync(out, 0, (size_t)Nd * 64 * 4, stream);
  score_k<<<(E + 3) / 4, 256, 0, stream>>>(fs, fd, attn, src, dst, sbuf, menc, E);
  expden_k<<<(E + 255) / 256, 256, 0, stream>>>(dst, menc, sbuf, den, E);
  aggr_k<<<(E + 3) / 4, 256, 0, stream>>>(fs, src, dst, sbuf, den, out, E);
}

extern "C" void kernel_launch(void* const* d_in, const int* in_sizes, int n_in,
                              void* d_out, int out_size, void* d_ws, size_t ws_size,
                              hipStream_t stream) {
  const float* user_emb = (const float*)d_in[0];
  const float* item_emb = (const float*)d_in[1];
  const int* rate_src = (const int*)d_in[2];
  const int* rate_dst = (const int*)d_in[3];
  const int* link_src = (const int*)d_in[4];
  const int* link_dst = (const int*)d_in[5];
  const int* neg_rate_src = (const int*)d_in[6];
  const int* neg_rate_dst = (const int*)d_in[7];
  const int* neg_link_src = (const int*)d_in[8];
  const int* neg_link_dst = (const int*)d_in[9];
  const float* lam = (const float*)d_in[10];
  const float* gat_Wsrc = (const float*)d_in[11];
  const float* gat_bsrc = (const float*)d_in[12];
  const float* gat_Wdst = (const float*)d_in[13];
  const float* gat_bdst = (const float*)d_in[14];
  const float* gat_attn = (const float*)d_in[15];
  const float* W_out = (const float*)d_in[16];
  const float* b_out = (const float*)d_in[17];
  const float* cheb_W = (const float*)d_in[18];
  const float* cheb_b = (const float*)d_in[19];
  const float* Wc = (const float*)d_in[20];
  const float* bc = (const float*)d_in[21];
  const float* Wsm = (const float*)d_in[22];
  const float* bs = (const float*)d_in[23];
  const float* WpP = (const float*)d_in[24];
  const float* bpP = (const float*)d_in[25];
  const float* WpS = (const float*)d_in[26];
  const float* bpS = (const float*)d_in[27];

  const int NU = in_sizes[0] / 64;
  const int NI = in_sizes[1] / 64;
  const int NR = in_sizes[2];
  const int NL = in_sizes[4];
  const int NMAX = NU > NI ? NU : NI;
  const size_t MAT = (size_t)NMAX * 64;

  float* ws = (float*)d_ws;
  float* B0 = ws + 0 * MAT;  // fs scratch / cheb h
  float* B1 = ws + 1 * MAT;  // fd scratch
  float* B2 = ws + 2 * MAT;  // h1_item -> T1 -> h_mP
  float* B3 = ws + 3 * MAT;  // h2_user -> T2 -> h_mS
  float* B4 = ws + 4 * MAT;  // item_infl -> h_uP
  float* B5 = ws + 5 * MAT;  // social_item -> h_uS
  float* B6 = ws + 6 * MAT;  // user_pref -> h_new_P
  float* B7 = ws + 7 * MAT;  // rst -> h_new_S
  float* B8 = ws + 8 * MAT;  // user_social
  float* sbuf = ws + 9 * MAT;                     // NR floats
  unsigned* menc = (unsigned*)(sbuf + NR);        // NU
  float* den = (float*)(menc + NU);               // NU
  float* dinv = den + NU;                         // NU (indeg then dinv)

  const int W64 = 64 * 64, B64 = 64;

  // ---- gat0: user -> item over rate edges ----
  run_gat(user_emb, NU, item_emb, NI,
          gat_Wsrc + 0 * W64, gat_bsrc + 0 * B64, gat_Wdst + 0 * W64,
          gat_bdst + 0 * B64, gat_attn + 0 * B64,
          rate_src, rate_dst, NR, B0, B1, B2, sbuf, menc, den, stream);
  // ---- gat1: item -> user (reverse rate) ----
  run_gat(item_emb, NI, user_emb, NU,
          gat_Wsrc + 1 * W64, gat_bsrc + 1 * B64, gat_Wdst + 1 * W64,
          gat_bdst + 1 * B64, gat_attn + 1 * B64,
          rate_dst, rate_src, NR, B0, B1, B3, sbuf, menc, den, stream);
  // ---- gat2: h1_item -> user (reverse rate) ----
  run_gat(B2, NI, user_emb, NU,
          gat_Wsrc + 2 * W64, gat_bsrc + 2 * B64, gat_Wdst + 2 * W64,
          gat_bdst + 2 * B64, gat_attn + 2 * B64,
          rate_dst, rate_src, NR, B0, B1, B4, sbuf, menc, den, stream);
  // ---- gat3: h2_user -> user over link edges ----
  run_gat(B3, NU, user_emb, NU,
          gat_Wsrc + 3 * W64, gat_bsrc + 3 * B64, gat_Wdst + 3 * W64,
          gat_bdst + 3 * B64, gat_attn + 3 * B64,
          link_src, link_dst, NL, B0, B1, B5, sbuf, menc, den, stream);
  // ---- user_pref = [item_infl, social_item] @ W_out + b_out -> B6 ----
  gemm128_k<<<GEMM_BLOCKS, 256, 0, stream>>>(B4, B5, W_out, b_out, B6, NU);

  // ---- ChebConv(k=3) on link graph ----
  hipMemsetAsync(dinv, 0, (size_t)NU * 4, stream);
  indeg_k<<<(NL + 255) / 256, 256, 0, stream>>>(link_dst, dinv, NL);
  dinv_k<<<(NU + 255) / 256, 256, 0, stream>>>(dinv, NU);
  const int TOT = NU * 64;
  // h = ahat(T0) -> B0 ; T1 -> B2
  hipMemsetAsync(B0, 0, (size_t)TOT * 4, stream);
  ahat_k<<<(NL + 3) / 4, 256, 0, stream>>>(user_emb, dinv, link_src, link_dst, B0, NL);
  t1_k<<<(TOT + 255) / 256, 256, 0, stream>>>(B0, user_emb, dinv, lam, B2, TOT);
  // h2 = ahat(T1) -> B0 ; T2 -> B3
  hipMemsetAsync(B0, 0, (size_t)TOT * 4, stream);
  ahat_k<<<(NL + 3) / 4, 256, 0, stream>>>(B2, dinv, link_src, link_dst, B0, NL);
  t2_k<<<(TOT + 255) / 256, 256, 0, stream>>>(B0, B2, user_emb, dinv, lam, B3, TOT);
  // rst = T0@W0 + T1@W1 + T2@W2 + b -> B7 (fused)
  cheb3_k<<<GEMM_BLOCKS, 256, 0, stream>>>(user_emb, B2, B3, cheb_W, cheb_b, B7, NU);

  // ---- gat4: rst -> rst over link edges -> user_social (B8) ----
  run_gat(B7, NU, B7, NU,
          gat_Wsrc + 4 * W64, gat_bsrc + 4 * B64, gat_Wdst + 4 * W64,
          gat_bdst + 4 * B64, gat_attn + 4 * B64,
          link_src, link_dst, NL, B0, B1, B8, sbuf, menc, den, stream);

  // ---- mutualistic ----
  gemm128_k<<<GEMM_BLOCKS, 256, 0, stream>>>(B6, user_emb, Wc, bc, B4, NU);   // h_uP
  gemm128_k<<<GEMM_BLOCKS, 256, 0, stream>>>(B8, user_emb, Wsm, bs, B5, NU);  // h_uS
  mut_k<<<(NU + 3) / 4, 256, 0, stream>>>(B4, B5, B2, B3, NU);                // h_mP, h_mS
  gemm128_k<<<GEMM_BLOCKS, 256, 0, stream>>>(B2, B4, WpP, bpP, B6, NU);       // h_new_P
  gemm128_k<<<GEMM_BLOCKS, 256, 0, stream>>>(B3, B5, WpS, bpS, B7, NU);       // h_new_S

  // ---- predictors ----
  float* out = (float*)d_out;
  dot_k<<<(NR + 3) / 4, 256, 0, stream>>>(B6, item_emb, rate_src, rate_dst, out, NR);
  dot_k<<<(NR + 3) / 4, 256, 0, stream>>>(B6, item_emb, neg_rate_src, neg_rate_dst, out + NR, NR);
  dot_k<<<(NL + 3) / 4, 256, 0, stream>>>(B7, user_emb, link_src, link_dst, out + 2 * (size_t)NR, NL);
  dot_k<<<(NL + 3) / 4, 256, 0, stream>>>(B7, user_emb, neg_link_src, neg_link_dst, out + 2 * (size_t)NR + NL, NL);
}